// Round 2
// baseline (990.020 us; speedup 1.0000x reference)
//
#include <hip/hip_runtime.h>
#include <hip/hip_bf16.h>

typedef unsigned short u16;
typedef __attribute__((ext_vector_type(8))) short short8;
typedef __attribute__((ext_vector_type(4))) float f32x4;
typedef __attribute__((ext_vector_type(8))) unsigned short ushort8v;

#define NVOX 200000
#define NOFF 27

__device__ __forceinline__ u16 f2bf(float f) {
    __hip_bfloat16 h = __float2bfloat16(f);
    return *reinterpret_cast<u16*>(&h);
}
__device__ __forceinline__ float bf2f(u16 u) {
    union { unsigned int i; float f; } v;
    v.i = ((unsigned int)u) << 16;
    return v.f;
}

// ---------------------------------------------------------------------------
// prep: cast x -> bf16 (vec4), transpose-cast W1/W2 -> [off][co][ci] bf16
// ---------------------------------------------------------------------------
__global__ __launch_bounds__(256) void prep_kernel(
    const float* __restrict__ x, const float* __restrict__ W1,
    const float* __restrict__ W2, u16* __restrict__ xb,
    u16* __restrict__ w1t, u16* __restrict__ w2t)
{
    const int XV = NVOX * 96 / 4;     // 4,800,000 vec4 jobs
    const int WE = NOFF * 96 * 192;   // 497,664
    int t = blockIdx.x * 256 + threadIdx.x;
    if (t < XV) {
        float4 v = *(const float4*)(x + (size_t)t * 4);
        ushort4 o;
        o.x = f2bf(v.x); o.y = f2bf(v.y); o.z = f2bf(v.z); o.w = f2bf(v.w);
        *(ushort4*)(xb + (size_t)t * 4) = o;
    } else if (t < XV + WE) {
        int e = t - XV;
        int off = e / 18432, rem = e % 18432;
        int co = rem / 96, ci = rem % 96;   // w1t: [off][co:192][ci:96]
        w1t[e] = f2bf(W1[off * 18432 + ci * 192 + co]);
    } else if (t < XV + 2 * WE) {
        int e = t - XV - WE;
        int off = e / 18432, rem = e % 18432;
        int co = rem / 192, ci = rem % 192; // w2t: [off][co:96][ci:192]
        w2t[e] = f2bf(W2[off * 18432 + ci * 96 + co]);
    }
}

// ---------------------------------------------------------------------------
// conv: explicit-GEMM sparse conv, bf16 MFMA, f32 accum.
//   CINST: staged K per phase (96), KSPLIT: phases per offset, COUT: out ch.
//   Block: 128 voxels x COUT, 512 threads = 8 waves in 4(m) x 2(n) grid.
//   Wave tile: 32 x (COUT/2) -> FM=2, FN=COUT/32 frags of 16x16.
// ---------------------------------------------------------------------------
template<int CINST, int KSPLIT, int COUT>
__global__ __launch_bounds__(512, 4) void conv_mfma(
    const u16* __restrict__ xb, const int* __restrict__ idxp,
    const int* __restrict__ mskp, const u16* __restrict__ Wt,
    u16* __restrict__ hout)
{
    constexpr int BM  = 128;
    constexpr int CIN = CINST * KSPLIT;   // full input channels (row stride)
    constexpr int RCH = CINST / 8;        // 16B chunks per staged row (12)
    constexpr int RP  = CINST + 8;        // padded LDS row in bf16 units (104)
    constexpr int FM  = 2;
    constexpr int FN  = COUT / 32;
    constexpr int KS  = CINST / 32;       // k-steps per phase (3)

    __shared__ u16 ldsA[BM * RP];
    __shared__ u16 ldsW[COUT * RP];
    __shared__ int lsrc[BM];

    const int tid  = threadIdx.x;
    const int row0 = blockIdx.x * BM;
    const int lane = tid & 63;
    const int wid  = tid >> 6;
    const int wm   = wid >> 1;            // 0..3
    const int wn   = wid & 1;             // 0..1
    const int lr   = lane & 15;
    const int lk   = lane >> 4;

    f32x4 acc[FM][FN];
#pragma unroll
    for (int m = 0; m < FM; ++m)
#pragma unroll
        for (int n = 0; n < FN; ++n)
            acc[m][n] = (f32x4){0.f, 0.f, 0.f, 0.f};

    const int aoff0 = (wm * 32 + lr) * RP + lk * 8;
    const int boff0 = (wn * (COUT / 2) + lr) * RP + lk * 8;

#pragma unroll 1
    for (int off = 0; off < NOFF; ++off) {
        __syncthreads();
        if (tid < BM) {
            int r = row0 + tid;
            int s = -1;
            if (r < NVOX && mskp[off * NVOX + r] > 0) s = idxp[off * NVOX + r];
            lsrc[tid] = s;
        }
        __syncthreads();
        const u16* wg = Wt + (size_t)off * (COUT * CIN);
#pragma unroll 1
        for (int hf = 0; hf < KSPLIT; ++hf) {
            if (hf > 0) __syncthreads();
            // stage A (masked gather): BM*RCH = 1536 chunks, 3 per thread
#pragma unroll
            for (int it = 0; it < (BM * RCH) / 512; ++it) {
                int l = it * 512 + tid;
                int r = l / RCH, c = l % RCH;
                int s = lsrc[r];
                uint4 v = {0u, 0u, 0u, 0u};
                if (s >= 0) v = *(const uint4*)(xb + s * CIN + hf * CINST + c * 8);
                *(uint4*)(ldsA + r * RP + c * 8) = v;
            }
            // stage W tile: COUT*RCH chunks
#pragma unroll
            for (int it = 0; it < (COUT * RCH + 511) / 512; ++it) {
                int l = it * 512 + tid;
                if (l < COUT * RCH) {
                    int co = l / RCH, c = l % RCH;
                    *(uint4*)(ldsW + co * RP + c * 8) =
                        *(const uint4*)(wg + co * CIN + hf * CINST + c * 8);
                }
            }
            __syncthreads();
#pragma unroll
            for (int ks = 0; ks < KS; ++ks) {
                short8 af[FM], bfr[FN];
#pragma unroll
                for (int m = 0; m < FM; ++m)
                    af[m] = *(const short8*)(ldsA + aoff0 + m * 16 * RP + ks * 32);
#pragma unroll
                for (int n = 0; n < FN; ++n)
                    bfr[n] = *(const short8*)(ldsW + boff0 + n * 16 * RP + ks * 32);
#pragma unroll
                for (int n = 0; n < FN; ++n)
#pragma unroll
                    for (int m = 0; m < FM; ++m)
                        acc[m][n] = __builtin_amdgcn_mfma_f32_16x16x32_bf16(
                            af[m], bfr[n], acc[m][n], 0, 0, 0);
            }
        }
    }

    // store bf16: D layout col=lane&15, row=(lane>>4)*4+q  [m89-verified]
#pragma unroll
    for (int m = 0; m < FM; ++m) {
#pragma unroll
        for (int q = 0; q < 4; ++q) {
            int row = row0 + wm * 32 + m * 16 + lk * 4 + q;
            if (row < NVOX) {
#pragma unroll
                for (int n = 0; n < FN; ++n) {
                    int col = wn * (COUT / 2) + n * 16 + lr;
                    hout[(size_t)row * COUT + col] = f2bf(acc[m][n][q]);
                }
            }
        }
    }
}

// ---------------------------------------------------------------------------
// BN stats pass A: per-block partial sum/sumsq per channel (no atomics)
//   grid 1024 blocks x 192 threads; part layout [b][2][COUT]
// ---------------------------------------------------------------------------
template<int COUT>
__global__ __launch_bounds__(192) void bn_statsA(
    const u16* __restrict__ h, float* __restrict__ part)
{
    constexpr int RPI = 192 / COUT;   // rows per iteration (1 or 2)
    constexpr int RPB = 196;          // rows per block (1024*196 >= 200000)
    const int t = threadIdx.x;
    const int c = t % COUT;
    const int ro = t / COUT;
    const int b = blockIdx.x;
    float s1 = 0.f, s2 = 0.f;
    int rend = (b + 1) * RPB; if (rend > NVOX) rend = NVOX;
    for (int r = b * RPB + ro; r < rend; r += RPI) {
        float v = bf2f(h[(size_t)r * COUT + c]);
        s1 += v; s2 += v * v;
    }
    __shared__ float sA[192], sB[192];
    sA[t] = s1; sB[t] = s2;
    __syncthreads();
    if (t < COUT) {
        float a = sA[t], q = sB[t];
        if (RPI == 2) { a += sA[t + COUT]; q += sB[t + COUT]; }
        part[b * 2 * COUT + t] = a;
        part[b * 2 * COUT + COUT + t] = q;
    }
}

// ---------------------------------------------------------------------------
// BN stats pass B: reduce partials over 1024 blocks, emit scale/shift
//   grid COUT blocks x 256 threads
// ---------------------------------------------------------------------------
template<int COUT>
__global__ __launch_bounds__(256) void bn_statsB(
    const float* __restrict__ part, const float* __restrict__ g,
    const float* __restrict__ bv, float* __restrict__ ss)
{
    const int c = blockIdx.x;
    const int t = threadIdx.x;
    float s1 = 0.f, s2 = 0.f;
    for (int b = t; b < 1024; b += 256) {
        s1 += part[b * 2 * COUT + c];
        s2 += part[b * 2 * COUT + COUT + c];
    }
#pragma unroll
    for (int d = 1; d < 64; d <<= 1) {
        s1 += __shfl_xor(s1, d);
        s2 += __shfl_xor(s2, d);
    }
    __shared__ float rs[8];
    int w = t >> 6;
    if ((t & 63) == 0) { rs[w] = s1; rs[4 + w] = s2; }
    __syncthreads();
    if (t == 0) {
        s1 = rs[0] + rs[1] + rs[2] + rs[3];
        s2 = rs[4] + rs[5] + rs[6] + rs[7];
        float mu  = s1 * (1.0f / NVOX);
        float var = s2 * (1.0f / NVOX) - mu * mu;
        float sc  = g[c] * rsqrtf(var + 1e-5f);
        ss[c] = sc;
        ss[COUT + c] = bv[c] - mu * sc;
    }
}

// ---------------------------------------------------------------------------
// apply BN + ReLU in place (bf16), vec8
// ---------------------------------------------------------------------------
template<int COUT>
__global__ __launch_bounds__(256) void bn_apply_relu(
    u16* __restrict__ h, const float* __restrict__ ss)
{
    int t = blockIdx.x * 256 + threadIdx.x;   // < NVOX*COUT/8
    int c0 = (t * 8) % COUT;
    ushort8v v = *(ushort8v*)(h + (size_t)t * 8);
#pragma unroll
    for (int j = 0; j < 8; ++j) {
        float f = bf2f(v[j]);
        f = fmaxf(f * ss[c0 + j] + ss[COUT + c0 + j], 0.f);
        v[j] = f2bf(f);
    }
    *(ushort8v*)(h + (size_t)t * 8) = v;
}

// ---------------------------------------------------------------------------
// final: out = relu(scale2*h2 + shift2 + x), f32 out, vec8
// ---------------------------------------------------------------------------
__global__ __launch_bounds__(256) void final_kernel(
    const u16* __restrict__ h2, const float* __restrict__ x,
    const float* __restrict__ ss, float* __restrict__ out)
{
    int t = blockIdx.x * 256 + threadIdx.x;   // < NVOX*96/8
    int c0 = (t * 8) % 96;
    ushort8v v = *(const ushort8v*)(h2 + (size_t)t * 8);
    float4 x0 = *(const float4*)(x + (size_t)t * 8);
    float4 x1 = *(const float4*)(x + (size_t)t * 8 + 4);
    float xs[8] = {x0.x, x0.y, x0.z, x0.w, x1.x, x1.y, x1.z, x1.w};
    float o[8];
#pragma unroll
    for (int j = 0; j < 8; ++j) {
        float f = bf2f(v[j]) * ss[c0 + j] + ss[96 + c0 + j] + xs[j];
        o[j] = fmaxf(f, 0.f);
    }
    *(float4*)(out + (size_t)t * 8)     = (float4){o[0], o[1], o[2], o[3]};
    *(float4*)(out + (size_t)t * 8 + 4) = (float4){o[4], o[5], o[6], o[7]};
}

// ---------------------------------------------------------------------------
extern "C" void kernel_launch(void* const* d_in, const int* in_sizes, int n_in,
                              void* d_out, int out_size, void* d_ws, size_t ws_size,
                              hipStream_t stream)
{
    const float* x    = (const float*)d_in[0];
    const int*   idx  = (const int*)d_in[1];
    const int*   mask = (const int*)d_in[2];
    const float* W1   = (const float*)d_in[3];
    const float* g1   = (const float*)d_in[4];
    const float* b1   = (const float*)d_in[5];
    const float* W2   = (const float*)d_in[6];
    const float* g2   = (const float*)d_in[7];
    const float* b2   = (const float*)d_in[8];

    unsigned char* ws = (unsigned char*)d_ws;
    u16*  xb   = (u16*)ws;                          // 38,400,000 B
    u16*  w1t  = (u16*)(ws + 38400000);             //    995,328 B
    u16*  w2t  = (u16*)(ws + 39395328);             //    995,328 B
    u16*  h2   = (u16*)(ws + 40390656);             // 38,400,000 B
    float* part = (float*)(ws + 78790656);          //  1,572,864 B
    float* ss1  = (float*)(ws + 80363520);          //      1,536 B
    float* ss2  = (float*)(ws + 80365056);          //        768 B

    u16* h = (u16*)d_out;         // reuse d_out (76.8MB) as [N][192] bf16

    prep_kernel<<<22638, 256, 0, stream>>>(x, W1, W2, xb, w1t, w2t);

    conv_mfma<96, 1, 192><<<1563, 512, 0, stream>>>(xb, idx, mask, w1t, h);
    bn_statsA<192><<<1024, 192, 0, stream>>>(h, part);
    bn_statsB<192><<<192, 256, 0, stream>>>(part, g1, b1, ss1);
    bn_apply_relu<192><<<18750, 256, 0, stream>>>(h, ss1);

    conv_mfma<96, 2, 96><<<1563, 512, 0, stream>>>(h, idx, mask, w2t, h2);
    bn_statsA<96><<<1024, 192, 0, stream>>>(h2, part);
    bn_statsB<96><<<96, 256, 0, stream>>>(part, g2, b2, ss2);
    final_kernel<<<9375, 256, 0, stream>>>(h2, x, ss2, (float*)d_out);
}